// Round 5
// baseline (236.562 us; speedup 1.0000x reference)
//
#include <hip/hip_runtime.h>
#include <stdint.h>

#define IN_F   8192
#define OUT_F  8192
#define MB     64
#define RANK   16
#define KSPLIT 4

typedef _Float16 f16x8 __attribute__((ext_vector_type(8)));
typedef _Float16 f16x2 __attribute__((ext_vector_type(2)));
typedef float    f32x4 __attribute__((ext_vector_type(4)));

__device__ __forceinline__ unsigned pk2h(float a, float b) {
    return __builtin_bit_cast(unsigned, __builtin_amdgcn_cvt_pkrtz(a, b));
}

// Decode 8 nvfp4 codes (dword p) -> f16x8 scaled by s2 (packed f16 pair).
// v_perm hi-byte LUT + sign bit3<<4. Verified across prior rounds.
__device__ __forceinline__ f16x8 decode8(unsigned p, unsigned s2) {
    unsigned q  = p >> 4;
    unsigned me = __builtin_amdgcn_perm(0x46444240u, 0x3E3C3800u, p & 0x07070707u);
    unsigned mo = __builtin_amdgcn_perm(0x46444240u, 0x3E3C3800u, q & 0x07070707u);
    unsigned he = ((p & 0x08080808u) << 4) | me;
    unsigned ho = ((q & 0x08080808u) << 4) | mo;
    unsigned bu0 = __builtin_amdgcn_perm(ho, he, 0x040C000Cu);
    unsigned bu1 = __builtin_amdgcn_perm(ho, he, 0x050C010Cu);
    unsigned bu2 = __builtin_amdgcn_perm(ho, he, 0x060C020Cu);
    unsigned bu3 = __builtin_amdgcn_perm(ho, he, 0x070C030Cu);
    f16x2 sv = __builtin_bit_cast(f16x2, s2);
    f16x2 h0 = __builtin_bit_cast(f16x2, bu0) * sv;
    f16x2 h1 = __builtin_bit_cast(f16x2, bu1) * sv;
    f16x2 h2 = __builtin_bit_cast(f16x2, bu2) * sv;
    f16x2 h3 = __builtin_bit_cast(f16x2, bu3) * sv;
    f16x8 b;
    b[0]=h0[0]; b[1]=h0[1]; b[2]=h1[0]; b[3]=h1[1];
    b[4]=h2[0]; b[5]=h2[1]; b[6]=h3[0]; b[7]=h3[1];
    return b;
}

// pack 4 source dwords (low byte each) -> 1 packed dword [b0(x),b0(y),b0(z),b0(w)]
__device__ __forceinline__ unsigned pack4(uint4 a) {
    unsigned t0 = __builtin_amdgcn_perm(a.y, a.x, 0x0C0C0400u);
    unsigned t1 = __builtin_amdgcn_perm(a.w, a.z, 0x0C0C0400u);
    return __builtin_amdgcn_perm(t1, t0, 0x05040100u);
}

// ---------------------------------------------------------------------------
// prep: grid (64 m, 4 kq). x quarter -> MFMA-A-fragment layout; t partials
// written per-kq (no atomics, no zero-init dependency on poisoned ws).
// ---------------------------------------------------------------------------
__global__ __launch_bounds__(256) void prep_kernel(
    const float* __restrict__ x, const float* __restrict__ lora_A,
    uint2* __restrict__ xf2, float* __restrict__ tp)
{
    const int m = blockIdx.x, kq = blockIdx.y;
    const int tid = threadIdx.x;
    const int mt = m >> 4, l15 = m & 15;
    float acc[RANK];
#pragma unroll
    for (int r = 0; r < RANK; ++r) acc[r] = 0.f;

    const float4* x4 = (const float4*)(x + (size_t)m * IN_F);
    const float4* A4 = (const float4*)lora_A;
#pragma unroll
    for (int it = 0; it < 2; ++it) {
        int j = kq * 512 + it * 256 + tid;
        float4 xv = x4[j];
        uint2 u;
        u.x = pk2h(xv.x, xv.y);
        u.y = pk2h(xv.z, xv.w);
        int kstep = j >> 3, quad = (j >> 1) & 3, h = j & 1;
        xf2[(size_t)(((kstep * 4 + mt) * 64 + quad * 16 + l15) * 2 + h)] = u;
#pragma unroll
        for (int r = 0; r < RANK; ++r) {
            float4 av = A4[(size_t)r * (IN_F / 4) + j];
            acc[r] += xv.x * av.x + xv.y * av.y + xv.z * av.z + xv.w * av.w;
        }
    }
#pragma unroll
    for (int r = 0; r < RANK; ++r)
#pragma unroll
        for (int off = 32; off > 0; off >>= 1)
            acc[r] += __shfl_down(acc[r], off);

    __shared__ float red[4][RANK];
    int lane = tid & 63, wid = tid >> 6;
    if (lane == 0) {
#pragma unroll
        for (int r = 0; r < RANK; ++r) red[wid][r] = acc[r];
    }
    __syncthreads();
    if (tid < RANK)
        tp[((size_t)kq * MB + m) * RANK + tid] =
            red[0][tid] + red[1][tid] + red[2][tid] + red[3][tid];
}

__device__ __forceinline__ float4 lora4(const float* __restrict__ tp, int m,
                                        const float* __restrict__ lora_B, int n4) {
    float ta[RANK];
#pragma unroll
    for (int r = 0; r < RANK; ++r) ta[r] = 0.f;
#pragma unroll
    for (int kq = 0; kq < 4; ++kq) {
        const float4* t4 = (const float4*)(tp + ((size_t)kq * MB + m) * RANK);
#pragma unroll
        for (int i = 0; i < 4; ++i) {
            float4 v = t4[i];
            ta[4*i+0] += v.x; ta[4*i+1] += v.y; ta[4*i+2] += v.z; ta[4*i+3] += v.w;
        }
    }
    float4 o;
    float* op = (float*)&o;
#pragma unroll
    for (int j = 0; j < 4; ++j) {
        const float4* B4 = (const float4*)(lora_B + (size_t)(n4 + j) * RANK);
        float s = 0.f;
#pragma unroll
        for (int i = 0; i < 4; ++i) {
            float4 b = B4[i];
            s += ta[4*i+0]*b.x + ta[4*i+1]*b.y + ta[4*i+2]*b.z + ta[4*i+3]*b.w;
        }
        op[j] = s;
    }
    return o;
}

__global__ __launch_bounds__(256) void lora_kernel(
    const float* __restrict__ tp, const float* __restrict__ lora_B,
    float* __restrict__ out)
{
    const int gid = blockIdx.x * 256 + threadIdx.x;
    ((float4*)out)[gid] = lora4(tp, gid >> 11, lora_B, (gid & 2047) * 4);
}

__global__ __launch_bounds__(256) void finish_kernel(
    const float* __restrict__ partial, const float* __restrict__ tp,
    const float* __restrict__ lora_B, float* __restrict__ out)
{
    const int gid = blockIdx.x * 256 + threadIdx.x;
    float4 p = {0.f, 0.f, 0.f, 0.f};
#pragma unroll
    for (int ksp = 0; ksp < KSPLIT; ++ksp) {
        float4 v = ((const float4*)partial)[(size_t)ksp * (MB * OUT_F / 4) + gid];
        p.x += v.x; p.y += v.y; p.z += v.z; p.w += v.w;
    }
    float4 l = lora4(tp, gid >> 11, lora_B, (gid & 2047) * 4);
    p.x += l.x; p.y += l.y; p.z += l.z; p.w += l.w;
    ((float4*)out)[gid] = p;
}

// ---------------------------------------------------------------------------
// main6: fused repack + GEMM + dequant, tiled for DRAM page locality.
// grid (KSPLIT=4, 128) = 512 blocks = 2/CU; block 256 = 4 waves.
// Block owns 64 rows x 64 m x 2048 k. W read ONCE, 4 KiB CONTIGUOUS per row
// per block (fmt1; 1 KiB fmt0), packed in-register, staged to a 64 KiB
// XOR-swizzled LDS tile (<=2-way bank aliasing = free). Scales packed to a
// 16 KiB LDS tile. Single barrier; compute loop touches only LDS + L2-hot xf.
// 80 KiB LDS -> 2 blocks/CU: one block computes while the other stages.
// No manual vmcnt (R2 lesson: FIFO coupling); compiler schedules waits.
// ---------------------------------------------------------------------------
template<int ATOMIC>
__global__ __launch_bounds__(256, 2) void main6_kernel(
    const void*  __restrict__ Wpv,
    const float* __restrict__ scales,
    const uint4* __restrict__ xf4,
    float*       __restrict__ dst)
{
    __shared__ __align__(16) unsigned wlds[64 * 256];   // 64 KiB packed W
    __shared__ __align__(16) unsigned slds[64 * 64];    // 16 KiB packed scales

    const int tid = threadIdx.x;
    const int lane = tid & 63, w = tid >> 6;
    const int l15 = lane & 15, quad = lane >> 4, qh = quad >> 1;
    const int ksp = blockIdx.x, by = blockIdx.y;
    const int nb = by * 64;                 // block row base
    const int rw = w * 16 + l15;            // this lane's LDS row (consumer)

    // format detect (wave-uniform, L2-broadcast)
    unsigned dv = ((const unsigned*)Wpv)[lane];
    const bool fmt1 = (__ballot(dv > 255u) == 0ull);

    const uint4* Wp4 = (const uint4*)Wpv;

    // ---- stage W: fully coalesced, long runs per row ----
    if (fmt1) {
        // 4 KiB contiguous per row; one row per round, 64 rounds
#pragma unroll 4
        for (int r = 0; r < 64; ++r) {
            uint4 a = Wp4[(size_t)(nb + r) * 1024 + ksp * 256 + tid];
            wlds[r * 256 + (tid ^ ((r & 7) << 2))] = pack4(a);
        }
    } else {
        // 1 KiB per row; 4 rows per round, 16 rounds
#pragma unroll 4
        for (int r = 0; r < 16; ++r) {
            int seg = r * 256 + tid;
            int row = seg >> 6, c16 = seg & 63;
            uint4 a = Wp4[(size_t)(nb + row) * 256 + ksp * 64 + c16];
            int base = row * 256, swz = (row & 7) << 2;
            wlds[base + ((c16 * 4 + 0) ^ swz)] = a.x;
            wlds[base + ((c16 * 4 + 1) ^ swz)] = a.y;
            wlds[base + ((c16 * 4 + 2) ^ swz)] = a.z;
            wlds[base + ((c16 * 4 + 3) ^ swz)] = a.w;
        }
    }

    // ---- stage scales: 512 B per row (f32) -> packed f16 pairs ----
#pragma unroll
    for (int r = 0; r < 8; ++r) {
        int seg = r * 256 + tid;
        int row = seg >> 5, u = seg & 31;
        float4 v = ((const float4*)(scales + (size_t)(nb + row) * (IN_F / 16)
                                    + ksp * 128))[u];
        int base = row * 64, swz = (row & 7) << 2;
        slds[base + ((2 * u + 0) ^ swz)] = pk2h(v.x, v.y);
        slds[base + ((2 * u + 1) ^ swz)] = pk2h(v.z, v.w);
    }
    __syncthreads();

    // ---- compute: 64 ksteps, LDS + L2-hot xf only ----
    f32x4 acc[4];
#pragma unroll
    for (int mt = 0; mt < 4; ++mt) acc[mt] = (f32x4){0.f, 0.f, 0.f, 0.f};

    const unsigned* wrow = &wlds[rw * 256];
    const unsigned* srow = &slds[rw * 64];
    const int wswz = (rw & 7) << 2;
    const unsigned ssel = qh ? 0x03020302u : 0x01000100u;  // splat hi/lo f16
    const uint4* xp = xf4 + (size_t)ksp * (64 * 4 * 64) + lane;

#pragma unroll 16
    for (int s = 0; s < 64; ++s) {
        f16x8 afr[4];
#pragma unroll
        for (int mt = 0; mt < 4; ++mt)
            afr[mt] = __builtin_bit_cast(f16x8, xp[(s * 4 + mt) * 64]);
        unsigned p  = wrow[(s * 4 + quad) ^ wswz];
        unsigned sd = srow[s ^ wswz];
        unsigned s2 = __builtin_amdgcn_perm(sd, sd, ssel);
        f16x8 b = decode8(p, s2);
#pragma unroll
        for (int mt = 0; mt < 4; ++mt)
            acc[mt] = __builtin_amdgcn_mfma_f32_16x16x32_f16(
                afr[mt], b, acc[mt], 0, 0, 0);
    }

    // epilogue: C/D col(n)=l15, row(m)=quad*4+r (+16*mt); n = nb + w*16 + l15
    const int ncol = nb + w * 16 + l15;
    if (ATOMIC == 0) {
        float* pb = dst + (size_t)ksp * (MB * OUT_F);
#pragma unroll
        for (int mt = 0; mt < 4; ++mt)
#pragma unroll
            for (int r = 0; r < 4; ++r)
                pb[(size_t)(mt * 16 + quad * 4 + r) * OUT_F + ncol] = acc[mt][r];
    } else {
#pragma unroll
        for (int mt = 0; mt < 4; ++mt)
#pragma unroll
            for (int r = 0; r < 4; ++r)
                atomicAdd(&dst[(size_t)(mt * 16 + quad * 4 + r) * OUT_F + ncol],
                          acc[mt][r]);
    }
}

extern "C" void kernel_launch(void* const* d_in, const int* in_sizes, int n_in,
                              void* d_out, int out_size, void* d_ws, size_t ws_size,
                              hipStream_t stream)
{
    (void)in_sizes; (void)n_in; (void)out_size;
    const float* x      = (const float*)d_in[0];
    const void*  Wp     = (const void*)d_in[1];
    const float* scales = (const float*)d_in[2];
    const float* lora_A = (const float*)d_in[3];
    const float* lora_B = (const float*)d_in[4];
    float* out = (float*)d_out;

    char* ws = (char*)d_ws;
    float* tp      = (float*)ws;                 // 16 KiB (4 kq x 64 m x 16 r)
    uint2* xf      = (uint2*)(ws + 65536);       // 1 MiB fragment-layout fp16 x
    float* partial = (float*)(ws + (2u << 20));  // KSPLIT * 2 MiB = 8 MiB
    const bool full = ws_size >= ((size_t)12 << 20);

    prep_kernel<<<dim3(64, 4), 256, 0, stream>>>(x, lora_A, xf, tp);

    if (full) {
        main6_kernel<0><<<dim3(KSPLIT, 128), 256, 0, stream>>>(
            Wp, scales, (const uint4*)xf, partial);
        finish_kernel<<<(MB * OUT_F / 4) / 256, 256, 0, stream>>>(
            partial, tp, lora_B, out);
    } else {
        lora_kernel<<<(MB * OUT_F / 4) / 256, 256, 0, stream>>>(tp, lora_B, out);
        main6_kernel<1><<<dim3(KSPLIT, 128), 256, 0, stream>>>(
            Wp, scales, (const uint4*)xf, out);
    }
}

// Round 6
// 233.853 us; speedup vs baseline: 1.0116x; 1.0116x over previous
//
#include <hip/hip_runtime.h>
#include <stdint.h>

#define IN_F   8192
#define OUT_F  8192
#define MB     64
#define RANK   16
#define KSPLIT 16

typedef _Float16 f16x8 __attribute__((ext_vector_type(8)));
typedef _Float16 f16x2 __attribute__((ext_vector_type(2)));
typedef float    f32x4 __attribute__((ext_vector_type(4)));

__device__ __forceinline__ unsigned pk2h(float a, float b) {
    return __builtin_bit_cast(unsigned, __builtin_amdgcn_cvt_pkrtz(a, b));
}

// Decode 8 nvfp4 codes (dword p) -> f16x8 scaled by s2 (packed f16 pair).
// v_perm hi-byte LUT + sign bit3<<4. Verified across prior rounds.
__device__ __forceinline__ f16x8 decode8(unsigned p, unsigned s2) {
    unsigned q  = p >> 4;
    unsigned me = __builtin_amdgcn_perm(0x46444240u, 0x3E3C3800u, p & 0x07070707u);
    unsigned mo = __builtin_amdgcn_perm(0x46444240u, 0x3E3C3800u, q & 0x07070707u);
    unsigned he = ((p & 0x08080808u) << 4) | me;
    unsigned ho = ((q & 0x08080808u) << 4) | mo;
    unsigned bu0 = __builtin_amdgcn_perm(ho, he, 0x040C000Cu);
    unsigned bu1 = __builtin_amdgcn_perm(ho, he, 0x050C010Cu);
    unsigned bu2 = __builtin_amdgcn_perm(ho, he, 0x060C020Cu);
    unsigned bu3 = __builtin_amdgcn_perm(ho, he, 0x070C030Cu);
    f16x2 sv = __builtin_bit_cast(f16x2, s2);
    f16x2 h0 = __builtin_bit_cast(f16x2, bu0) * sv;
    f16x2 h1 = __builtin_bit_cast(f16x2, bu1) * sv;
    f16x2 h2 = __builtin_bit_cast(f16x2, bu2) * sv;
    f16x2 h3 = __builtin_bit_cast(f16x2, bu3) * sv;
    f16x8 b;
    b[0]=h0[0]; b[1]=h0[1]; b[2]=h1[0]; b[3]=h1[1];
    b[4]=h2[0]; b[5]=h2[1]; b[6]=h3[0]; b[7]=h3[1];
    return b;
}

// pack 4 source dwords (low byte each) -> 1 packed dword [b0(x),b0(y),b0(z),b0(w)]
__device__ __forceinline__ unsigned pack4(uint4 a) {
    unsigned t0 = __builtin_amdgcn_perm(a.y, a.x, 0x0C0C0400u);
    unsigned t1 = __builtin_amdgcn_perm(a.w, a.z, 0x0C0C0400u);
    return __builtin_amdgcn_perm(t1, t0, 0x05040100u);
}

// ---------------------------------------------------------------------------
// prep: grid (64 m, 4 kq). x quarter -> MFMA-A-fragment layout; t partials
// written per-kq (no atomics, no zero-init dependency on poisoned ws).
// ---------------------------------------------------------------------------
__global__ __launch_bounds__(256) void prep_kernel(
    const float* __restrict__ x, const float* __restrict__ lora_A,
    uint2* __restrict__ xf2, float* __restrict__ tp)
{
    const int m = blockIdx.x, kq = blockIdx.y;
    const int tid = threadIdx.x;
    const int mt = m >> 4, l15 = m & 15;
    float acc[RANK];
#pragma unroll
    for (int r = 0; r < RANK; ++r) acc[r] = 0.f;

    const float4* x4 = (const float4*)(x + (size_t)m * IN_F);
    const float4* A4 = (const float4*)lora_A;
#pragma unroll
    for (int it = 0; it < 2; ++it) {
        int j = kq * 512 + it * 256 + tid;
        float4 xv = x4[j];
        uint2 u;
        u.x = pk2h(xv.x, xv.y);
        u.y = pk2h(xv.z, xv.w);
        int kstep = j >> 3, quad = (j >> 1) & 3, h = j & 1;
        xf2[(size_t)(((kstep * 4 + mt) * 64 + quad * 16 + l15) * 2 + h)] = u;
#pragma unroll
        for (int r = 0; r < RANK; ++r) {
            float4 av = A4[(size_t)r * (IN_F / 4) + j];
            acc[r] += xv.x * av.x + xv.y * av.y + xv.z * av.z + xv.w * av.w;
        }
    }
#pragma unroll
    for (int r = 0; r < RANK; ++r)
#pragma unroll
        for (int off = 32; off > 0; off >>= 1)
            acc[r] += __shfl_down(acc[r], off);

    __shared__ float red[4][RANK];
    int lane = tid & 63, wid = tid >> 6;
    if (lane == 0) {
#pragma unroll
        for (int r = 0; r < RANK; ++r) red[wid][r] = acc[r];
    }
    __syncthreads();
    if (tid < RANK)
        tp[((size_t)kq * MB + m) * RANK + tid] =
            red[0][tid] + red[1][tid] + red[2][tid] + red[3][tid];
}

__device__ __forceinline__ float4 lora4(const float* __restrict__ tp, int m,
                                        const float* __restrict__ lora_B, int n4) {
    float ta[RANK];
#pragma unroll
    for (int r = 0; r < RANK; ++r) ta[r] = 0.f;
#pragma unroll
    for (int kq = 0; kq < 4; ++kq) {
        const float4* t4 = (const float4*)(tp + ((size_t)kq * MB + m) * RANK);
#pragma unroll
        for (int i = 0; i < 4; ++i) {
            float4 v = t4[i];
            ta[4*i+0] += v.x; ta[4*i+1] += v.y; ta[4*i+2] += v.z; ta[4*i+3] += v.w;
        }
    }
    float4 o;
    float* op = (float*)&o;
#pragma unroll
    for (int j = 0; j < 4; ++j) {
        const float4* B4 = (const float4*)(lora_B + (size_t)(n4 + j) * RANK);
        float s = 0.f;
#pragma unroll
        for (int i = 0; i < 4; ++i) {
            float4 b = B4[i];
            s += ta[4*i+0]*b.x + ta[4*i+1]*b.y + ta[4*i+2]*b.z + ta[4*i+3]*b.w;
        }
        op[j] = s;
    }
    return o;
}

__global__ __launch_bounds__(256) void lora_kernel(
    const float* __restrict__ tp, const float* __restrict__ lora_B,
    float* __restrict__ out)
{
    const int gid = blockIdx.x * 256 + threadIdx.x;
    ((float4*)out)[gid] = lora4(tp, gid >> 11, lora_B, (gid & 2047) * 4);
}

__global__ __launch_bounds__(256) void finish_kernel(
    const float* __restrict__ partial, const float* __restrict__ tp,
    const float* __restrict__ lora_B, float* __restrict__ out)
{
    const int gid = blockIdx.x * 256 + threadIdx.x;
    float4 p = {0.f, 0.f, 0.f, 0.f};
#pragma unroll
    for (int ksp = 0; ksp < KSPLIT; ++ksp) {
        float4 v = ((const float4*)partial)[(size_t)ksp * (MB * OUT_F / 4) + gid];
        p.x += v.x; p.y += v.y; p.z += v.z; p.w += v.w;
    }
    float4 l = lora4(tp, gid >> 11, lora_B, (gid & 2047) * 4);
    p.x += l.x; p.y += l.y; p.z += l.z; p.w += l.w;
    ((float4*)out)[gid] = p;
}

// ---------------------------------------------------------------------------
// main7: fused repack + GEMM + dequant.
// grid (KSPLIT=16, 32) = 512 blocks = 1/CU (128 KiB LDS), block 512 = 8 waves.
// Block: 256 rows x 64 m x 512 k; wave owns 32 rows.
// - xs (x fragments, 64 KiB) staged once; single barrier; compute reads LDS only.
// - W staged wave-private into wlds[w] (8 KiB/wave): loads are 128 B
//   CONTIGUOUS PER LANE, 8 consecutive lanes per row -> full-line requests,
//   512 B per row in flight per half. Two k-halves; half-1 loads issue right
//   after the barrier and fly under half-0 compute. No manual vmcnt (R2
//   lesson): all W deps are intra-wave, compiler inserts counted waits.
// - Grid (16,32): all 32 blocks of one ksp land on one XCD (id%8 = ksp%8),
//   so the 64 KiB xs slice is read from XCD-local L2.
// ---------------------------------------------------------------------------
template<int ATOMIC>
__global__ __launch_bounds__(512, 2) void main7_kernel(
    const void*  __restrict__ Wpv,
    const float* __restrict__ scales,
    const uint4* __restrict__ xf4,
    float*       __restrict__ dst)
{
    __shared__ __align__(16) uint4    xs[4096];         // 64 KiB x fragments
    __shared__ __align__(16) unsigned wlds[8][32][64];  // 64 KiB packed W

    const int tid = threadIdx.x;
    const int lane = tid & 63, w = tid >> 6;
    const int l15 = lane & 15, quad = lane >> 4, qh = quad >> 1;
    const int ks = blockIdx.x, by = blockIdx.y;
    const int n0 = by * 256 + w * 32;                   // wave row base
    const int lr8 = lane >> 3, lc8 = lane & 7;          // fmt1 staging split
    const int lr2 = lane >> 1, lc2 = lane & 1;          // fmt0 staging split

    // format detect (wave-uniform, L2-broadcast)
    unsigned dv = ((const unsigned*)Wpv)[lane];
    const bool fmt1 = (__ballot(dv > 255u) == 0ull);

    const uint4* Wp4 = (const uint4*)Wpv;
    uint4 lt[16];

    // LOADW half h: wave's 32 rows x 32 packed dwords, long contiguous runs
#define LOADW(h)                                                              \
    do {                                                                      \
        if (fmt1) {                                                           \
            _Pragma("unroll") for (int p = 0; p < 4; ++p)                     \
            _Pragma("unroll") for (int i = 0; i < 4; ++i)                     \
                lt[p * 4 + i] = Wp4[(size_t)(n0 + p * 8 + lr8) * 1024         \
                                    + ks * 64 + (h) * 32 + i * 8 + lc8];      \
        } else {                                                              \
            _Pragma("unroll") for (int i = 0; i < 4; ++i)                     \
                lt[i] = Wp4[(size_t)(n0 + lr2) * 256                          \
                            + ks * 16 + (h) * 8 + i * 2 + lc2];              \
        }                                                                     \
    } while (0)

#define WRITEW(h)                                                             \
    do {                                                                      \
        if (fmt1) {                                                           \
            _Pragma("unroll") for (int p = 0; p < 4; ++p) {                   \
                int rl = p * 8 + lr8, sw = (rl & 7) << 2;                     \
                _Pragma("unroll") for (int i = 0; i < 4; ++i)                 \
                    wlds[w][rl][((h) * 32 + i * 8 + lc8) ^ sw]                \
                        = pack4(lt[p * 4 + i]);                               \
            }                                                                 \
        } else {                                                              \
            int rl = lr2, sw = (rl & 7) << 2;                                 \
            _Pragma("unroll") for (int i = 0; i < 4; ++i) {                   \
                int d0 = ((h) * 8 + i * 2 + lc2) * 4;                         \
                wlds[w][rl][(d0 + 0) ^ sw] = lt[i].x;                         \
                wlds[w][rl][(d0 + 1) ^ sw] = lt[i].y;                         \
                wlds[w][rl][(d0 + 2) ^ sw] = lt[i].z;                         \
                wlds[w][rl][(d0 + 3) ^ sw] = lt[i].w;                         \
            }                                                                 \
        }                                                                     \
    } while (0)

    // ---- prologue: xs + W half 0, one barrier ----
    uint4 xr[8];
    {
        const uint4* gsrc = xf4 + (size_t)ks * 4096;
#pragma unroll
        for (int i = 0; i < 8; ++i) xr[i] = gsrc[i * 512 + tid];
    }
    LOADW(0);

    // ---- scale preload: 32 packed-f16 dwords (this lane's qh parity) ----
    unsigned sreg[2][16];
#pragma unroll
    for (int nt = 0; nt < 2; ++nt) {
        const float4* sp = (const float4*)(scales
                           + (size_t)(n0 + nt * 16 + l15) * (IN_F / 16) + ks * 32);
#pragma unroll
        for (int i = 0; i < 8; ++i) {
            float4 vv = sp[i];
            float a = qh ? vv.y : vv.x, b = qh ? vv.w : vv.z;
            sreg[nt][2 * i]     = pk2h(a, a);
            sreg[nt][2 * i + 1] = pk2h(b, b);
        }
    }

#pragma unroll
    for (int i = 0; i < 8; ++i) xs[i * 512 + tid] = xr[i];
    WRITEW(0);
    __syncthreads();

    f32x4 acc[4][2];
#pragma unroll
    for (int mt = 0; mt < 4; ++mt)
#pragma unroll
        for (int nt = 0; nt < 2; ++nt)
            acc[mt][nt] = (f32x4){0.f, 0.f, 0.f, 0.f};

    // issue W half 1 now; it flies under half-0 compute (intra-wave dep only)
    LOADW(1);

#define COMPUTE(h)                                                            \
    do {                                                                      \
        _Pragma("unroll") for (int sc = 0; sc < 8; ++sc) {                    \
            const int s = (h) * 8 + sc;                                       \
            f16x8 afr[4];                                                     \
            _Pragma("unroll") for (int mt = 0; mt < 4; ++mt)                  \
                afr[mt] = __builtin_bit_cast(f16x8, xs[(s * 4 + mt) * 64 + lane]); \
            _Pragma("unroll") for (int nt = 0; nt < 2; ++nt) {                \
                int rl = nt * 16 + l15;                                       \
                unsigned p = wlds[w][rl][(s * 4 + quad) ^ ((rl & 7) << 2)];   \
                f16x8 b = decode8(p, sreg[nt][s]);                            \
                _Pragma("unroll") for (int mt = 0; mt < 4; ++mt)              \
                    acc[mt][nt] = __builtin_amdgcn_mfma_f32_16x16x32_f16(     \
                        afr[mt], b, acc[mt][nt], 0, 0, 0);                    \
            }                                                                 \
        }                                                                     \
    } while (0)

    COMPUTE(0);
    WRITEW(1);      // compiler waits lt loads (vmcnt) then LDS writes
    COMPUTE(1);     // compiler waits lgkmcnt for wave-private writes

#undef LOADW
#undef WRITEW
#undef COMPUTE

    // epilogue: C/D col(n)=l15, row(m)=quad*4+r (+16*mt)
    if (ATOMIC == 0) {
        float* pb = dst + (size_t)ks * (MB * OUT_F);
#pragma unroll
        for (int mt = 0; mt < 4; ++mt)
#pragma unroll
            for (int nt = 0; nt < 2; ++nt)
#pragma unroll
                for (int r = 0; r < 4; ++r)
                    pb[(size_t)(mt * 16 + quad * 4 + r) * OUT_F
                       + n0 + nt * 16 + l15] = acc[mt][nt][r];
    } else {
#pragma unroll
        for (int mt = 0; mt < 4; ++mt)
#pragma unroll
            for (int nt = 0; nt < 2; ++nt)
#pragma unroll
                for (int r = 0; r < 4; ++r)
                    atomicAdd(&dst[(size_t)(mt * 16 + quad * 4 + r) * OUT_F
                                   + n0 + nt * 16 + l15], acc[mt][nt][r]);
    }
}

extern "C" void kernel_launch(void* const* d_in, const int* in_sizes, int n_in,
                              void* d_out, int out_size, void* d_ws, size_t ws_size,
                              hipStream_t stream)
{
    (void)in_sizes; (void)n_in; (void)out_size;
    const float* x      = (const float*)d_in[0];
    const void*  Wp     = (const void*)d_in[1];
    const float* scales = (const float*)d_in[2];
    const float* lora_A = (const float*)d_in[3];
    const float* lora_B = (const float*)d_in[4];
    float* out = (float*)d_out;

    char* ws = (char*)d_ws;
    float* tp      = (float*)ws;                 // 16 KiB (4 kq x 64 m x 16 r)
    uint2* xf      = (uint2*)(ws + 65536);       // 1 MiB fragment-layout fp16 x
    float* partial = (float*)(ws + (2u << 20));  // KSPLIT * 2 MiB = 32 MiB
    const bool full = ws_size >= ((size_t)34 << 20);

    prep_kernel<<<dim3(64, 4), 256, 0, stream>>>(x, lora_A, xf, tp);

    if (full) {
        main7_kernel<0><<<dim3(KSPLIT, 32), 512, 0, stream>>>(
            Wp, scales, (const uint4*)xf, partial);
        finish_kernel<<<(MB * OUT_F / 4) / 256, 256, 0, stream>>>(
            partial, tp, lora_B, out);
    } else {
        lora_kernel<<<(MB * OUT_F / 4) / 256, 256, 0, stream>>>(tp, lora_B, out);
        main7_kernel<1><<<dim3(KSPLIT, 32), 512, 0, stream>>>(
            Wp, scales, (const uint4*)xf, out);
    }
}